// Round 2
// baseline (1177.173 us; speedup 1.0000x reference)
//
#include <hip/hip_runtime.h>
#include <math.h>

#define N_NODES 661
#define N_GRAPH 128
#define DEG 8
#define EPG (N_NODES*DEG)          // 5288 edges per graph per matrix
#define NTOT (N_NODES*N_GRAPH)     // 84608 nodes
#define FDIM 64
#define NF ((size_t)NTOT*FDIM)     // elements per [n,64] array
#define OSTR 672                   // padded CSR offsets stride (662 used)

// ws layout (4-byte units):
//   arrs     : 8*NF floats   [e3, ne, e1, e2, f3, nf, f1, f2]
//   partials : 1024 floats   [g][8] attention dot partials (atomic)
//   att      : 1024 floats   [g][8] normalized attention weights
//   Wt1,Wt2  : 20480 each    W transposed-packed [k4][o][4]
//   offs     : 512*OSTR ints CSR row offsets per (matrix,graph)
//   pairs    : 512*EPG int2  CSR sorted (col, val-bits)

// ---------------------------------------------------------------------------
// Kernel 0: transpose-pack W1/W2 into [k4][o][4]; zero attention partials
// ---------------------------------------------------------------------------
__global__ __launch_bounds__(256) void wtrans(
    const float* __restrict__ W1, const float* __restrict__ W2,
    float* __restrict__ Wt1, float* __restrict__ Wt2,
    float* __restrict__ partials)
{
    int i = blockIdx.x*256 + threadIdx.x;     // 0..20479
    if (i < 20480) {
        int k4 = i >> 8, rem = i & 255;
        int o = rem >> 2, kk = rem & 3;
        int k = k4*4 + kk;
        Wt1[i] = W1[o*320 + k];
        Wt2[i] = W2[o*320 + k];
    }
    if (blockIdx.x == 0) {
        for (int j = threadIdx.x; j < 1024; j += 256) partials[j] = 0.f;
    }
}

// ---------------------------------------------------------------------------
// Kernel 1: per-(graph,matrix) counting sort in LDS -> CSR in global ws
// ---------------------------------------------------------------------------
__global__ __launch_bounds__(256) void csr_build(
    const int* __restrict__ rG, const int* __restrict__ cG, const float* __restrict__ vG,
    const int* __restrict__ rB, const int* __restrict__ cB, const float* __restrict__ vB,
    const int* __restrict__ r1, const int* __restrict__ c1, const float* __restrict__ v1,
    const int* __restrict__ r2, const int* __restrict__ c2, const float* __restrict__ v2,
    int* __restrict__ offs_out, int2* __restrict__ pairs_out)
{
    __shared__ int   scount[N_NODES];
    __shared__ int   soffs[N_NODES+1];
    __shared__ int   scursor[N_NODES];
    __shared__ int   scol[EPG];
    __shared__ float sval[EPG];
    __shared__ int   spart[256];

    int bid = blockIdx.x;
    int g = bid & 127;
    int m = bid >> 7;
    const int*   rows = (m==0)?rG:(m==1)?rB:(m==2)?r1:r2;
    const int*   cols = (m==0)?cG:(m==1)?cB:(m==2)?c1:c2;
    const float* vals = (m==0)?vG:(m==1)?vB:(m==2)?v1:v2;

    int tid = threadIdx.x;
    int ebase = g*EPG;
    int gbase = g*N_NODES;
    int seg = m*N_GRAPH + g;

    for (int i = tid; i < N_NODES; i += 256) scount[i] = 0;
    __syncthreads();
    for (int i = tid; i < EPG; i += 256)
        atomicAdd(&scount[rows[ebase+i] - gbase], 1);
    __syncthreads();

    // prefix scan over 661 counts
    int c0 = tid*3;
    int ps = 0;
    #pragma unroll
    for (int j = 0; j < 3; ++j) { int i = c0+j; if (i < N_NODES) ps += scount[i]; }
    spart[tid] = ps;
    __syncthreads();
    if (tid == 0) {
        int run = 0;
        for (int i = 0; i < 256; ++i) { int t = spart[i]; spart[i] = run; run += t; }
        soffs[N_NODES] = EPG;
    }
    __syncthreads();
    int run = spart[tid];
    #pragma unroll
    for (int j = 0; j < 3; ++j) {
        int i = c0+j;
        if (i < N_NODES) { soffs[i] = run; scursor[i] = run; run += scount[i]; }
    }
    __syncthreads();
    for (int i = tid; i < EPG; i += 256) {
        int r = rows[ebase+i] - gbase;
        int pos = atomicAdd(&scursor[r], 1);
        scol[pos] = cols[ebase+i];
        sval[pos] = vals[ebase+i];
    }
    __syncthreads();

    // coalesced write-out
    for (int i = tid; i <= N_NODES; i += 256)
        offs_out[(size_t)seg*OSTR + i] = soffs[i];
    int2* po = pairs_out + (size_t)seg*EPG;
    for (int i = tid; i < EPG; i += 256)
        po[i] = make_int2(scol[i], __float_as_int(sval[i]));
}

// ---------------------------------------------------------------------------
// shared elementwise math (matches reference)
// ---------------------------------------------------------------------------
__device__ __forceinline__ void node_math(
    float ev, float fv, float gd, float bd, float pd, float qd,
    float eGv, float fGv, float eBv, float fBv,
    float& e3v, float& nev, float& f3v, float& nfv)
{
    float invb = 1.0f/(ev*ev + fv*fv + 0.1f);
    float alpha = (pd*ev + qd*fv)*invb - eGv - fBv;
    float beta  = (qd*ev - pd*fv)*invb + fGv + eBv;
    float invg = 1.0f/(gd*gd + bd*bd);
    e3v = (alpha*gd + beta*bd)*invg;
    f3v = (beta*gd - alpha*bd)*invg;
    float bb1 = eGv - fBv, bb2 = fGv + eBv;
    float vv = ev*ev + fv*fv;
    float P_ = pd - vv*gd, Q_ = qd + vv*bd;
    nev = (P_*bb1 + Q_*bb2)*invg;
    nfv = (P_*bb2 - Q_*bb1)*invg;
}

// ---------------------------------------------------------------------------
// Kernel 2: one wave per row; gather-SpMM over all 4 matrices + node math +
// attention partials. Writes [e3, ne, e1, e2, f3, nf, f1, f2].
// ---------------------------------------------------------------------------
__global__ __launch_bounds__(256) void spmm_fused(
    const float* __restrict__ e, const float* __restrict__ f,
    const float* __restrict__ Gd, const float* __restrict__ Bd,
    const float* __restrict__ Pd, const float* __restrict__ Qd,
    const float* __restrict__ w_ae, const float* __restrict__ w_af,
    const int* __restrict__ offs, const int2* __restrict__ pairs,
    float* __restrict__ arrs, float* __restrict__ partials)
{
    int tid = threadIdx.x, lane = tid & 63, wv = tid >> 6;
    int node = blockIdx.x*4 + wv;          // grid = NTOT/4, always in range
    int g = node / N_NODES;
    int r = node - g*N_NODES;
    size_t idx = (size_t)node*FDIM + lane;

    float acc[8];
    #pragma unroll
    for (int j = 0; j < 8; ++j) acc[j] = 0.f;

    #pragma unroll
    for (int m = 0; m < 4; ++m) {
        int seg = m*N_GRAPH + g;
        const int* po = offs + (size_t)seg*OSTR;
        int s = po[r], t = po[r+1];
        const int2* pp = pairs + (size_t)seg*EPG;
        for (int k = s; k < t; ++k) {
            int2 p = pp[k];
            float v = __int_as_float(p.y);
            size_t ci = (size_t)p.x*FDIM + lane;
            acc[2*m]   = fmaf(v, e[ci], acc[2*m]);
            acc[2*m+1] = fmaf(v, f[ci], acc[2*m+1]);
        }
    }

    float ev = e[idx], fv = f[idx];
    float gd = Gd[node], bd = Bd[node], pd = Pd[node], qd = Qd[node];
    float e3v, nev, f3v, nfv;
    node_math(ev, fv, gd, bd, pd, qd, acc[0], acc[1], acc[2], acc[3],
              e3v, nev, f3v, nfv);

    arrs[0*NF + idx] = e3v;
    arrs[1*NF + idx] = nev;
    arrs[2*NF + idx] = acc[4];   // e1
    arrs[3*NF + idx] = acc[6];   // e2
    arrs[4*NF + idx] = f3v;
    arrs[5*NF + idx] = nfv;
    arrs[6*NF + idx] = acc[5];   // f1
    arrs[7*NF + idx] = acc[7];   // f2

    // attention partials: dot with w over (nodes, features), atomically per graph
    float wa = w_ae[lane], wf = w_af[lane];
    float pa[8];
    pa[0] = e3v*wa; pa[1] = nev*wa; pa[2] = acc[4]*wa; pa[3] = acc[6]*wa;
    pa[4] = f3v*wf; pa[5] = nfv*wf; pa[6] = acc[5]*wf; pa[7] = acc[7]*wf;
    #pragma unroll
    for (int j = 0; j < 8; ++j) {
        float v = pa[j];
        for (int off = 32; off > 0; off >>= 1) v += __shfl_down(v, off);
        if (lane == 0) atomicAdd(&partials[g*8 + j], v);
    }
}

// ---------------------------------------------------------------------------
// Kernel 3: finalize attention weights (sigmoid + normalize)
// ---------------------------------------------------------------------------
__global__ void attn_final(const float* __restrict__ partials,
                           const float* __restrict__ b_ae, const float* __restrict__ b_af,
                           float* __restrict__ att)
{
    int g = threadIdx.x;
    if (g >= N_GRAPH) return;
    float ae[4], af[4], se = 1e-4f, sf = 1e-4f;
    float bae = b_ae[0], baf = b_af[0];
    #pragma unroll
    for (int j = 0; j < 4; ++j) {
        float x = partials[g*8 + j]*(1.0f/N_NODES) + bae;
        ae[j] = 1.0f/(1.0f + expf(-x)); se += ae[j];
        float y = partials[g*8 + 4 + j]*(1.0f/N_NODES) + baf;
        af[j] = 1.0f/(1.0f + expf(-y)); sf += af[j];
    }
    #pragma unroll
    for (int j = 0; j < 4; ++j) {
        att[g*8 + j]     = ae[j]/se;
        att[g*8 + 4 + j] = af[j]/sf;
    }
}

// ---------------------------------------------------------------------------
// Kernel 4: build cat vectors in LDS (precomputed arrays * att), fused GEMM+tanh
// W pre-transposed to [k4][o][4] so W loads are lane-coalesced float4.
// ---------------------------------------------------------------------------
#define STR 324  // 320 padded; 324*4 bytes keeps float4 alignment per row
__global__ __launch_bounds__(256) void final_fused(
    const float* __restrict__ e, const float* __restrict__ f,
    const float* __restrict__ arrs, const float* __restrict__ att,
    const float* __restrict__ Wt1, const float* __restrict__ bv1,
    const float* __restrict__ Wt2, const float* __restrict__ bv2,
    float* __restrict__ out)
{
    __shared__ __align__(16) float cat_e[16*STR];
    __shared__ __align__(16) float cat_f[16*STR];

    int tid = threadIdx.x, lane = tid & 63, chunk = tid >> 6;
    int node0 = blockIdx.x * 16;

    #pragma unroll
    for (int round = 0; round < 4; ++round) {
        int ni = round*4 + chunk;
        int node = node0 + ni;
        int g = node / N_NODES;
        size_t idx = (size_t)node*FDIM + lane;
        float* ce = &cat_e[ni*STR];
        float* cf = &cat_f[ni*STR];
        ce[lane]     = arrs[0*NF + idx]*att[g*8+0];
        ce[64+lane]  = arrs[1*NF + idx]*att[g*8+1];
        ce[128+lane] = arrs[2*NF + idx]*att[g*8+2];
        ce[192+lane] = arrs[3*NF + idx]*att[g*8+3];
        ce[256+lane] = e[idx];
        cf[lane]     = arrs[4*NF + idx]*att[g*8+4];
        cf[64+lane]  = arrs[5*NF + idx]*att[g*8+5];
        cf[128+lane] = arrs[6*NF + idx]*att[g*8+6];
        cf[192+lane] = arrs[7*NF + idx]*att[g*8+7];
        cf[256+lane] = f[idx];
    }
    __syncthreads();

    float ae[4], af[4];
    #pragma unroll
    for (int j = 0; j < 4; ++j) { ae[j] = bv1[lane]; af[j] = bv2[lane]; }

    for (int k4 = 0; k4 < 80; ++k4) {
        float4 w1 = *(const float4*)(Wt1 + (size_t)k4*256 + lane*4);
        float4 w2 = *(const float4*)(Wt2 + (size_t)k4*256 + lane*4);
        #pragma unroll
        for (int j = 0; j < 4; ++j) {
            int ni = chunk*4 + j;
            float4 cev = *(const float4*)(&cat_e[ni*STR + k4*4]);
            float4 cfv = *(const float4*)(&cat_f[ni*STR + k4*4]);
            ae[j] = fmaf(cev.x, w1.x, fmaf(cev.y, w1.y, fmaf(cev.z, w1.z, fmaf(cev.w, w1.w, ae[j]))));
            af[j] = fmaf(cfv.x, w2.x, fmaf(cfv.y, w2.y, fmaf(cfv.z, w2.z, fmaf(cfv.w, w2.w, af[j]))));
        }
    }
    #pragma unroll
    for (int j = 0; j < 4; ++j) {
        int node = node0 + chunk*4 + j;
        out[(size_t)node*FDIM + lane]      = tanhf(ae[j]);
        out[NF + (size_t)node*FDIM + lane] = tanhf(af[j]);
    }
}

// ---------------------------------------------------------------------------
extern "C" void kernel_launch(void* const* d_in, const int* in_sizes, int n_in,
                              void* d_out, int out_size, void* d_ws, size_t ws_size,
                              hipStream_t stream) {
    (void)in_sizes; (void)n_in; (void)out_size; (void)ws_size;
    const float* e     = (const float*)d_in[0];
    const float* f     = (const float*)d_in[1];
    const int*   rowsG = (const int*)d_in[2];
    const int*   colsG = (const int*)d_in[3];
    const float* valsG = (const float*)d_in[4];
    const int*   rowsB = (const int*)d_in[5];
    const int*   colsB = (const int*)d_in[6];
    const float* valsB = (const float*)d_in[7];
    const int*   rows1 = (const int*)d_in[8];
    const int*   cols1 = (const int*)d_in[9];
    const float* vals1 = (const float*)d_in[10];
    const int*   rows2 = (const int*)d_in[11];
    const int*   cols2 = (const int*)d_in[12];
    const float* vals2 = (const float*)d_in[13];
    const float* G_d   = (const float*)d_in[14];
    const float* B_d   = (const float*)d_in[15];
    const float* Pd    = (const float*)d_in[16];
    const float* Qd    = (const float*)d_in[17];
    const float* W1    = (const float*)d_in[18];
    const float* b1    = (const float*)d_in[19];
    const float* W2    = (const float*)d_in[20];
    const float* b2    = (const float*)d_in[21];
    const float* w_ae  = (const float*)d_in[22];
    const float* b_ae  = (const float*)d_in[23];
    const float* w_af  = (const float*)d_in[24];
    const float* b_af  = (const float*)d_in[25];

    float* ws       = (float*)d_ws;
    float* arrs     = ws;                         // 8*NF
    float* partials = ws + 8*NF;                  // 1024
    float* att      = partials + 1024;            // 1024
    float* Wt1      = att + 1024;                 // 20480
    float* Wt2      = Wt1 + 20480;                // 20480
    int*   offs     = (int*)(Wt2 + 20480);        // 512*OSTR
    int2*  pairs    = (int2*)(offs + 512*OSTR);   // 512*EPG

    wtrans<<<dim3(80), dim3(256), 0, stream>>>(W1, W2, Wt1, Wt2, partials);

    csr_build<<<dim3(512), dim3(256), 0, stream>>>(
        rowsG, colsG, valsG, rowsB, colsB, valsB,
        rows1, cols1, vals1, rows2, cols2, vals2, offs, pairs);

    spmm_fused<<<dim3(NTOT/4), dim3(256), 0, stream>>>(
        e, f, G_d, B_d, Pd, Qd, w_ae, w_af, offs, pairs, arrs, partials);

    attn_final<<<dim3(1), dim3(128), 0, stream>>>(partials, b_ae, b_af, att);

    final_fused<<<dim3(NTOT/16), dim3(256), 0, stream>>>(
        e, f, arrs, att, Wt1, b1, Wt2, b2, (float*)d_out);
}